// Round 8
// baseline (785.284 us; speedup 1.0000x reference)
//
#include <hip/hip_runtime.h>
#include <math.h>

#define NB 96
#define NA 48
#define NF 128
#define NK 64
#define NL 6
#define NN (NB*NA)     // 4608 nodes
#define F3 (3*NF)      // 384
#define CUTF 5.0f
#define GAMMA_F ((float)(1.0 / (0.006103515625 + 1e-9)))
#define PI_F 3.14159265358979323846f

typedef __attribute__((ext_vector_type(8))) short short8;
typedef __attribute__((ext_vector_type(4))) float floatx4;
typedef __attribute__((ext_vector_type(2))) float floatx2;

#define LO2(v) __builtin_shufflevector(v, v, 0, 1)
#define HI2(v) __builtin_shufflevector(v, v, 2, 3)

// phi/vT tile layout: [graph][mt][384 features][16 j]  (wave load = 1KB contiguous)
#define PHX(g, mt, ff, jl) (((((size_t)(g))*3 + (mt))*384 + (ff))*16 + (jl))

__device__ __forceinline__ float silu_f(float x) { return x / (1.0f + expf(-x)); }

__device__ __forceinline__ short f2bf(float x) {
    unsigned u = __builtin_bit_cast(unsigned, x);
    unsigned r = (u + 0x7fffu + ((u >> 16) & 1u)) >> 16;   // RNE
    return (short)r;
}
__device__ __forceinline__ float bf2f(short h) {
    unsigned u = ((unsigned)(unsigned short)h) << 16;
    return __builtin_bit_cast(float, u);
}
__device__ __forceinline__ floatx4 mfma1(short8 a, short8 b, floatx4 c) {
    return __builtin_amdgcn_mfma_f32_16x16x32_bf16(a, b, c, 0, 0, 0);
}
__device__ __forceinline__ floatx4 mfma3(short8 ah, short8 al, short8 bh, short8 bl, floatx4 c) {
    c = __builtin_amdgcn_mfma_f32_16x16x32_bf16(ah, bh, c, 0, 0, 0);
    c = __builtin_amdgcn_mfma_f32_16x16x32_bf16(al, bh, c, 0, 0, 0);
    c = __builtin_amdgcn_mfma_f32_16x16x32_bf16(ah, bl, c, 0, 0, 0);
    return c;
}

// async global->LDS, 16B/lane; lds dest must be wave-uniform base + lane*16
__device__ __forceinline__ void gload_lds16(const void* g, void* l) {
    __builtin_amdgcn_global_load_lds(
        (const __attribute__((address_space(1))) unsigned int*)g,
        (__attribute__((address_space(3))) unsigned int*)l, 16, 0, 0);
}

// ---------------- fused prep: weights -> bf16 hi/lo in MFMA B-FRAGMENT ORDER ----------------
__global__ void prep_kernel(const float* __restrict__ msg_w1, const float* __restrict__ msg_w2,
                            const float* __restrict__ rbf_w, const float* __restrict__ upd_U,
                            const float* __restrict__ upd_V, const float* __restrict__ upd_w1,
                            const float* __restrict__ upd_w2,
                            short* w1T_h, short* w1T_l, short* w2T_h, short* w2T_l,
                            short* rbfT_h, short* rbfT_l, short* UT_h, short* UT_l,
                            short* VT_h, short* VT_l, short* u1T_h, short* u1T_l,
                            short* u2T_h, short* u2T_l) {
    int m = blockIdx.y;
    int l = blockIdx.x / 384;
    int n = blockIdx.x % 384;
    const float* src; short* dh; short* dl; int K, N;
    switch (m) {
      case 0: src = msg_w1; dh = w1T_h; dl = w1T_l; K = NF;   N = NF; break;
      case 1: src = msg_w2; dh = w2T_h; dl = w2T_l; K = NF;   N = F3; break;
      case 2: src = rbf_w;  dh = rbfT_h;dl = rbfT_l;K = NK;   N = F3; break;
      case 3: src = upd_U;  dh = UT_h;  dl = UT_l;  K = NF;   N = NF; break;
      case 4: src = upd_V;  dh = VT_h;  dl = VT_l;  K = NF;   N = NF; break;
      case 5: src = upd_w1; dh = u1T_h; dl = u1T_l; K = 2*NF; N = NF; break;
      default:src = upd_w2; dh = u2T_h; dl = u2T_l; K = NF;   N = F3; break;
    }
    if (n >= N) return;
    for (int k = threadIdx.x; k < K; k += 64) {
        float x = src[((size_t)l*K + k)*N + n];
        short h = f2bf(x);
        size_t off = (size_t)l*N*K
                   + (size_t)((((n>>4)*(K>>5) + (k>>5))*4 + ((k>>3)&3))*128 + (n&15)*8 + (k&7));
        dh[off] = h;
        dl[off] = f2bf(x - bf2f(h));
    }
}

// ---------------- geometry (once): we, dir per (i,j) + rbf*we in tkL FRAGMENT ORDER ----------------
__global__ void __launch_bounds__(256) geom_kernel(const float* __restrict__ pos,
                                                   float* __restrict__ weG,
                                                   float* __restrict__ dirG,
                                                   short* __restrict__ rbfP) {
    int e = blockIdx.x*256 + threadIdx.x;        // e < NN*NA
    int i = e / NA, j = e % NA;
    int b = i / NA, il = i % NA;
    int jg = b*NA + j;
    float dx = pos[i*3+0] - pos[jg*3+0];
    float dy = pos[i*3+1] - pos[jg*3+1];
    float dz = pos[i*3+2] - pos[jg*3+2];
    float d2 = dx*dx + dy*dy + dz*dz;
    float dd = sqrtf((j == il) ? 1.0f : d2);     // matches where(eye,1,d2)
    bool valid = (j != il) && (dd < CUTF);
    float we = valid ? 0.5f*(cosf(PI_F * dd / CUTF) + 1.0f) : 0.0f;
    weG[e] = we;
    float inv = 1.0f / dd;
    dirG[0*(size_t)NN*NA + e] = dx*inv;
    dirG[1*(size_t)NN*NA + e] = dy*inv;
    dirG[2*(size_t)NN*NA + e] = dz*inv;
    int mt = j >> 4, colj = j & 15;
    size_t rb = (size_t)i*3072 + (size_t)(mt*2)*512 + (size_t)colj*8;
    #pragma unroll
    for (int half = 0; half < 2; ++half) {
        #pragma unroll
        for (int c = 0; c < 4; ++c) {
            short8 h8;
            #pragma unroll
            for (int kk = 0; kk < 8; ++kk) {
                int k = half*32 + c*8 + kk;
                float cen = CUTF * (float)k / 63.0f;
                float df = dd - cen;
                h8[kk] = f2bf(__expf(-GAMMA_F * df * df) * we);
            }
            *(short8*)&rbfP[rb + half*512 + c*128] = h8;
        }
    }
}

__global__ void zero_kernel(float* __restrict__ p) {
    p[(size_t)blockIdx.x * blockDim.x + threadIdx.x] = 0.f;
}

// ---------------- init + phi(0) ----------------
__global__ void __launch_bounds__(128) init_phi_kernel(
        const float* __restrict__ emb, const int* __restrict__ node_atom,
        const short* __restrict__ w1T_h, const short* __restrict__ w1T_l,
        const float* __restrict__ b1,
        const short* __restrict__ w2T_h, const short* __restrict__ w2T_l,
        const float* __restrict__ b2,
        float* __restrict__ s, float* __restrict__ v, float* __restrict__ phiX) {
    __shared__ short sH[16*NF], sL[16*NF];
    __shared__ short hH[16*NF], hL[16*NF];
    int t = threadIdx.x;
    int w = t >> 6, lane = t & 63, quad = lane >> 4, col = lane & 15;
    int n0 = blockIdx.x * 16;
    int g = n0 / NA, mt0 = (n0 % NA) >> 4;      // 16-node block lies in one mt
    for (int e = t; e < 16*NF; e += 128) {
        int n = e >> 7, f = e & 127;
        int a = node_atom[n0+n];
        float x = emb[(size_t)a*NF + f];
        s[(size_t)(n0+n)*NF + f] = x;
        short h = f2bf(x);
        int ad = n*NF + (((f >> 3) ^ (n & 7)) << 3) + (f & 7);
        sH[ad] = h; sL[ad] = f2bf(x - bf2f(h));
    }
    for (int e = t; e < 16*F3; e += 128) v[(size_t)n0*F3 + e] = 0.f;
    __syncthreads();
    #pragma unroll
    for (int nt = 0; nt < 4; ++nt) {
        int fh = w*64 + nt*16 + col;
        floatx4 acc = (floatx4){0.f,0.f,0.f,0.f};
        #pragma unroll
        for (int ks = 0; ks < 4; ++ks) {
            int ad = col*NF + (((ks*4 + quad) ^ (col & 7)) << 3);
            size_t off = (size_t)((((w*4 + nt)*4 + ks)*4 + quad)*128) + col*8;
            acc = mfma3(*(short8*)&sH[ad], *(short8*)&sL[ad],
                        *(const short8*)(w1T_h + off), *(const short8*)(w1T_l + off), acc);
        }
        float bias = b1[fh];
        #pragma unroll
        for (int r = 0; r < 4; ++r) {
            int n = quad*4 + r;
            float hv = silu_f(acc[r] + bias);
            short h = f2bf(hv);
            int ad = n*NF + (((fh >> 3) ^ (n & 7)) << 3) + (fh & 7);
            hH[ad] = h; hL[ad] = f2bf(hv - bf2f(h));
        }
    }
    __syncthreads();
    #pragma unroll
    for (int nt = 0; nt < 12; ++nt) {
        int tt = w*192 + nt*16 + col;
        floatx4 acc = (floatx4){0.f,0.f,0.f,0.f};
        #pragma unroll
        for (int ks = 0; ks < 4; ++ks) {
            int ad = col*NF + (((ks*4 + quad) ^ (col & 7)) << 3);
            size_t off = (size_t)((((w*12 + nt)*4 + ks)*4 + quad)*128) + col*8;
            acc = mfma3(*(short8*)&hH[ad], *(short8*)&hL[ad],
                        *(const short8*)(w2T_h + off), *(const short8*)(w2T_l + off), acc);
        }
        float bias = b2[tt];
        floatx4 o;
        #pragma unroll
        for (int r = 0; r < 4; ++r) o[r] = acc[r] + bias;
        *(floatx4*)(phiX + PHX(g, mt0, tt, quad*4)) = o;
    }
}

// ---------------- message: block = (graph, 6-atom tile), 512 thr ----------------
// R8 = R7 + 2-stage software pipeline on the phi/vX vector loads across the mt
// loop: prefetch mt+1's 6 floatx4 before computing mt's ia-loop, so the
// ~200-600cy L2/L3 latency hides under ~2000cy of MFMA+combine. +24 VGPR
// (~96-104, under the (512,2) cap of 128).
__global__ void __launch_bounds__(512, 2) message_kernel(
        const float* __restrict__ sIn, const float* __restrict__ vIn,
        const float* __restrict__ phiX, const float* __restrict__ vX,
        const float* __restrict__ weG, const float* __restrict__ dirG,
        const short* __restrict__ rbfP,
        const short* __restrict__ rbfT_h,
        const float* __restrict__ rbf_b_l,
        float* __restrict__ sOut, float* __restrict__ vOut) {
    __shared__ short tkL[36*512];           // 36 KB: 6 atoms x 3 mt x 2 halves x 512
    __shared__ float weL[6][NA];
    __shared__ float dirL[3][6][NA];
    int raw = blockIdx.x;                   // 768 = 8 xcd x 12 graphs x 8 tiles
    int xcd = raw & 7, idx = raw >> 3;
    int graph = xcd + 8*(idx % 12);
    int itile = idx / 12;                   // 0..7
    int i0l = itile*6, jbase = graph*NA;
    int n0 = jbase + i0l;
    int t = threadIdx.x;
    int w = t >> 6, lane = t & 63, quad = lane >> 4, col = lane & 15;
    int f = w*16 + col;
    // async stage rbfP -> tkL: 2304 x 16B, 4 full rounds + 256 tail (waves 0..3)
    {
        const char* gsrc = (const char*)(rbfP + (size_t)n0*3072);
        #pragma unroll
        for (int it = 0; it < 4; ++it)
            gload_lds16(gsrc + (size_t)(t + it*512)*16, (char*)tkL + (size_t)(w*64 + it*512)*16);
        if (w < 4)
            gload_lds16(gsrc + (size_t)(2048 + t)*16, (char*)tkL + (size_t)(2048 + w*64)*16);
    }
    if (t < 288) {
        int ii = t / NA, j = t % NA;
        size_t e = (size_t)(n0 + ii)*NA + j;
        weL[ii][j] = weG[e];
        dirL[0][ii][j] = dirG[0*(size_t)NN*NA + e];
        dirL[1][ii][j] = dirG[1*(size_t)NN*NA + e];
        dirL[2][ii][j] = dirG[2*(size_t)NN*NA + e];
    }
    float rb0 = rbf_b_l[f], rb1 = rbf_b_l[NF+f], rb2 = rbf_b_l[2*NF+f];
    floatx2 rb0v = {rb0, rb0}, rb1v = {rb1, rb1}, rb2v = {rb2, rb2};
    short8 B[3][2];
    #pragma unroll
    for (int g = 0; g < 3; ++g)
        #pragma unroll
        for (int ks = 0; ks < 2; ++ks)
            B[g][ks] = *(const short8*)(rbfT_h + (size_t)((((g*8 + w)*2 + ks)*4 + quad)*128) + col*8);
    __syncthreads();
    float accS[6], av0[6], av1[6], av2[6];
    #pragma unroll
    for (int ia = 0; ia < 6; ++ia) { accS[ia]=0.f; av0[ia]=0.f; av1[ia]=0.f; av2[ia]=0.f; }
    int jq = quad*4;
    // prefetch mt=0
    floatx4 p0 = *(const floatx4*)(phiX + PHX(graph, 0, f, jq));
    floatx4 p1 = *(const floatx4*)(phiX + PHX(graph, 0, NF+f, jq));
    floatx4 p2 = *(const floatx4*)(phiX + PHX(graph, 0, 2*NF+f, jq));
    floatx4 u0 = *(const floatx4*)(vX + PHX(graph, 0, 0*NF+f, jq));
    floatx4 u1 = *(const floatx4*)(vX + PHX(graph, 0, 1*NF+f, jq));
    floatx4 u2 = *(const floatx4*)(vX + PHX(graph, 0, 2*NF+f, jq));
    #pragma unroll 1
    for (int mt = 0; mt < 3; ++mt) {
        floatx4 q0, q1, q2, x0, x1v, x2v;
        if (mt < 2) {                        // issue next-mt loads BEFORE compute
            q0  = *(const floatx4*)(phiX + PHX(graph, mt+1, f, jq));
            q1  = *(const floatx4*)(phiX + PHX(graph, mt+1, NF+f, jq));
            q2  = *(const floatx4*)(phiX + PHX(graph, mt+1, 2*NF+f, jq));
            x0  = *(const floatx4*)(vX + PHX(graph, mt+1, 0*NF+f, jq));
            x1v = *(const floatx4*)(vX + PHX(graph, mt+1, 1*NF+f, jq));
            x2v = *(const floatx4*)(vX + PHX(graph, mt+1, 2*NF+f, jq));
        }
        int jl = mt*16 + quad*4;
        #pragma unroll
        for (int ia = 0; ia < 6; ++ia) {
            floatx4 C0 = (floatx4){0.f,0.f,0.f,0.f};
            floatx4 C1 = (floatx4){0.f,0.f,0.f,0.f};
            floatx4 C2 = (floatx4){0.f,0.f,0.f,0.f};
            #pragma unroll
            for (int ks = 0; ks < 2; ++ks) {
                short8 a = *(short8*)&tkL[(((ia*3 + mt)*2 + ks) << 9) + lane*8];
                C0 = mfma1(a, B[0][ks], C0);
                C1 = mfma1(a, B[1][ks], C1);
                C2 = mfma1(a, B[2][ks], C2);
            }
            floatx4 we4 = *(const floatx4*)&weL[ia][jl];
            floatx4 d0 = *(const floatx4*)&dirL[0][ia][jl];
            floatx4 d1 = *(const floatx4*)&dirL[1][ia][jl];
            floatx4 d2 = *(const floatx4*)&dirL[2][ia][jl];
            floatx2 aS = {0.f,0.f}, a0 = {0.f,0.f}, a1 = {0.f,0.f}, a2 = {0.f,0.f};
            // packed pair 0 (r = 0,1)
            {
                floatx2 we2 = LO2(we4);
                floatx2 Wf0 = rb0v*we2 + LO2(C0);
                aS += LO2(p0) * Wf0;
                floatx2 Wf1 = rb1v*we2 + LO2(C1);
                floatx2 x1 = LO2(p1) * Wf1;
                a0 += x1 * LO2(u0);
                a1 += x1 * LO2(u1);
                a2 += x1 * LO2(u2);
                floatx2 Wf2 = rb2v*we2 + LO2(C2);
                floatx2 x2 = LO2(p2) * Wf2;
                a0 += x2 * LO2(d0);
                a1 += x2 * LO2(d1);
                a2 += x2 * LO2(d2);
            }
            // packed pair 1 (r = 2,3)
            {
                floatx2 we2 = HI2(we4);
                floatx2 Wf0 = rb0v*we2 + HI2(C0);
                aS += HI2(p0) * Wf0;
                floatx2 Wf1 = rb1v*we2 + HI2(C1);
                floatx2 x1 = HI2(p1) * Wf1;
                a0 += x1 * HI2(u0);
                a1 += x1 * HI2(u1);
                a2 += x1 * HI2(u2);
                floatx2 Wf2 = rb2v*we2 + HI2(C2);
                floatx2 x2 = HI2(p2) * Wf2;
                a0 += x2 * HI2(d0);
                a1 += x2 * HI2(d1);
                a2 += x2 * HI2(d2);
            }
            accS[ia] += aS.x + aS.y;
            av0[ia]  += a0.x + a0.y;
            av1[ia]  += a1.x + a1.y;
            av2[ia]  += a2.x + a2.y;
        }
        if (mt < 2) {                        // rotate pipeline registers
            p0 = q0; p1 = q1; p2 = q2;
            u0 = x0; u1 = x1v; u2 = x2v;
        }
    }
    #pragma unroll
    for (int ia = 0; ia < 6; ++ia) {
        int i = n0 + ia;
        float aS = accS[ia], A0 = av0[ia], A1 = av1[ia], A2 = av2[ia];
        aS += __shfl_xor(aS, 16, 64); aS += __shfl_xor(aS, 32, 64);
        A0 += __shfl_xor(A0, 16, 64); A0 += __shfl_xor(A0, 32, 64);
        A1 += __shfl_xor(A1, 16, 64); A1 += __shfl_xor(A1, 32, 64);
        A2 += __shfl_xor(A2, 16, 64); A2 += __shfl_xor(A2, 32, 64);
        if (quad == 0) {
            sOut[(size_t)i*NF + f]        = sIn[(size_t)i*NF + f]        + aS;
            vOut[(size_t)i*F3 + f]        = vIn[(size_t)i*F3 + f]        + A0;
            vOut[(size_t)i*F3 + NF + f]   = vIn[(size_t)i*F3 + NF + f]   + A1;
            vOut[(size_t)i*F3 + 2*NF + f] = vIn[(size_t)i*F3 + 2*NF + f] + A2;
        }
    }
}

// ---------------- update (+ fused phi): 6 nodes/block, 512 thr, hi-only GEMMs ----------------
__global__ void __launch_bounds__(512) update_phi_kernel(
        const short* __restrict__ UT_h, const short* __restrict__ VT_h,
        const short* __restrict__ u1T_h, const float* __restrict__ b1,
        const short* __restrict__ u2T_h, const float* __restrict__ b2,
        float* __restrict__ s, float* __restrict__ v, float* __restrict__ vX,
        int doPhi,
        const short* __restrict__ pw1_h, const float* __restrict__ pb1,
        const short* __restrict__ pw2_h, const float* __restrict__ pb2,
        float* __restrict__ phiX) {
    __shared__ short A1h[48*NF], A1l[48*NF];   // v (hi for MFMA, hi+lo for epilogue reconstruct)
    __shared__ short A2h[16*256];              // [s ; Vn] hi; reused for s_new (phi A)
    __shared__ short hH[16*NF];
    __shared__ float sF[6*132];
    int t = threadIdx.x;
    int w = t >> 6, lane = t & 63, quad = lane >> 4, col = lane & 15;
    int raw = blockIdx.x;                   // 768 = 8 xcd x 12 graphs x 8 tiles
    int xcd = raw & 7, idx = raw >> 3;
    int graph = xcd + 8*(idx % 12);
    int jb0 = (idx / 12)*6;                 // local node base within graph
    int n0 = graph*NA + jb0;
    int f = w*16 + col;
    for (int e = t; e < 6*F3; e += 512) {
        int n = e / F3, cf = e % F3;
        int c = cf >> 7, ff = cf & 127;
        float x = v[(size_t)(n0+n)*F3 + cf];
        int row = c*16 + n;
        short h = f2bf(x);
        int ad = row*NF + (((ff >> 3) ^ (row & 7)) << 3) + (ff & 7);
        A1h[ad] = h; A1l[ad] = f2bf(x - bf2f(h));
    }
    for (int e = t; e < 6*NF; e += 512) {
        int n = e >> 7, ff = e & 127;
        float x = s[(size_t)(n0+n)*NF + ff];
        sF[n*132 + ff] = x;
        int ad = n*256 + (((ff >> 3) ^ (n & 7)) << 3) + (ff & 7);
        A2h[ad] = f2bf(x);
    }
    __syncthreads();
    floatx4 Uacc[3], Vacc[3];
    #pragma unroll
    for (int mt = 0; mt < 3; ++mt) { Uacc[mt] = (floatx4){0.f,0.f,0.f,0.f}; Vacc[mt] = (floatx4){0.f,0.f,0.f,0.f}; }
    #pragma unroll
    for (int ks = 0; ks < 4; ++ks) {
        size_t off = (size_t)(((w*4 + ks)*4 + quad)*128) + col*8;
        short8 BU = *(const short8*)(UT_h + off);
        short8 BV = *(const short8*)(VT_h + off);
        #pragma unroll
        for (int mt = 0; mt < 3; ++mt) {
            int row = mt*16 + col;
            int ad = row*NF + (((ks*4 + quad) ^ (row & 7)) << 3);
            short8 ah = *(short8*)&A1h[ad];
            Uacc[mt] = mfma1(ah, BU, Uacc[mt]);
            Vacc[mt] = mfma1(ah, BV, Vacc[mt]);
        }
    }
    if (quad < 2) {
        #pragma unroll
        for (int r = 0; r < 4; ++r) {
            int n = quad*4 + r;          // n < 8
            if (n < 6) {
                float v0 = Vacc[0][r], v1 = Vacc[1][r], v2 = Vacc[2][r];
                float vn = sqrtf(v0*v0 + v1*v1 + v2*v2 + 1e-8f);
                int ad = n*256 + ((((128 + f) >> 3) ^ (n & 7)) << 3) + (f & 7);
                A2h[ad] = f2bf(vn);
            }
        }
    }
    __syncthreads();
    {
        floatx4 H = (floatx4){0.f,0.f,0.f,0.f};
        #pragma unroll
        for (int ks = 0; ks < 8; ++ks) {
            int ad = col*256 + (((ks*4 + quad) ^ (col & 7)) << 3);
            short8 ah = *(short8*)&A2h[ad];
            size_t off = (size_t)(((w*8 + ks)*4 + quad)*128) + col*8;
            H = mfma1(ah, *(const short8*)(u1T_h + off), H);
        }
        float bias = b1[f];
        if (quad < 2) {
            #pragma unroll
            for (int r = 0; r < 4; ++r) {
                int n = quad*4 + r;
                if (n < 6) {
                    float hv = silu_f(H[r] + bias);
                    int ad = n*NF + (((f >> 3) ^ (n & 7)) << 3) + (f & 7);
                    hH[ad] = f2bf(hv);
                }
            }
        }
    }
    __syncthreads();
    floatx4 O[3];
    #pragma unroll
    for (int gg = 0; gg < 3; ++gg) O[gg] = (floatx4){0.f,0.f,0.f,0.f};
    #pragma unroll
    for (int ks = 0; ks < 4; ++ks) {
        int ad = col*NF + (((ks*4 + quad) ^ (col & 7)) << 3);
        short8 ah = *(short8*)&hH[ad];
        #pragma unroll
        for (int gg = 0; gg < 3; ++gg) {
            size_t off = (size_t)((((gg*8 + w)*4 + ks)*4 + quad)*128) + col*8;
            O[gg] = mfma1(ah, *(const short8*)(u2T_h + off), O[gg]);
        }
    }
    __syncthreads();        // A2h free -> reuse for s_new (phi A operand)
    short* pH = A2h;
    if (quad < 2) {
        float bavv = b2[f], basv = b2[NF + f], bass = b2[2*NF + f];
        #pragma unroll
        for (int r = 0; r < 4; ++r) {
            int n = quad*4 + r;          // n < 8
            if (n < 6) {
                float avv = O[0][r] + bavv;
                float asv = O[1][r] + basv;
                float ass = O[2][r] + bass;
                float dot = Uacc[0][r]*Vacc[0][r] + Uacc[1][r]*Vacc[1][r] + Uacc[2][r]*Vacc[2][r];
                float snew = sF[n*132 + f] + asv*dot + ass;
                s[(size_t)(n0+n)*NF + f] = snew;
                int adS = n*NF + (((f >> 3) ^ (n & 7)) << 3) + (f & 7);
                pH[adS] = f2bf(snew);
                int jl = jb0 + n;
                int mtt = jl >> 4, jl16 = jl & 15;
                #pragma unroll
                for (int c = 0; c < 3; ++c) {
                    int row = c*16 + n;
                    int ad = row*NF + (((f >> 3) ^ (row & 7)) << 3) + (f & 7);
                    float vold = bf2f(A1h[ad]) + bf2f(A1l[ad]);   // exact fp32 v_old
                    float vnew = vold + avv*Uacc[c][r];
                    v[(size_t)(n0+n)*F3 + c*NF + f] = vnew;
                    vX[PHX(graph, mtt, c*NF + f, jl16)] = vnew;
                }
            }
        }
    }
    if (!doPhi) return;
    __syncthreads();
    // phi GEMM1: wave w -> feature tile w (fh = w*16+col)
    {
        floatx4 acc = (floatx4){0.f,0.f,0.f,0.f};
        #pragma unroll
        for (int ks = 0; ks < 4; ++ks) {
            int ad = col*NF + (((ks*4 + quad) ^ (col & 7)) << 3);
            size_t off = (size_t)(((w*4 + ks)*4 + quad)*128) + col*8;
            acc = mfma1(*(short8*)&pH[ad], *(const short8*)(pw1_h + off), acc);
        }
        float bias = pb1[f];
        if (quad < 2) {
            #pragma unroll
            for (int r = 0; r < 4; ++r) {
                int n = quad*4 + r;
                if (n < 6) {
                    float hv = silu_f(acc[r] + bias);
                    int ad = n*NF + (((f >> 3) ^ (n & 7)) << 3) + (f & 7);
                    hH[ad] = f2bf(hv);
                }
            }
        }
    }
    __syncthreads();
    // phi GEMM2: 8 waves x 3 tiles (tt = (w*3+nt)*16 + col)
    #pragma unroll
    for (int nt = 0; nt < 3; ++nt) {
        int tt = (w*3 + nt)*16 + col;
        floatx4 acc = (floatx4){0.f,0.f,0.f,0.f};
        #pragma unroll
        for (int ks = 0; ks < 4; ++ks) {
            int ad = col*NF + (((ks*4 + quad) ^ (col & 7)) << 3);
            size_t off = (size_t)((((w*3 + nt)*4 + ks)*4 + quad)*128) + col*8;
            acc = mfma1(*(short8*)&hH[ad], *(const short8*)(pw2_h + off), acc);
        }
        float bias = pb2[tt];
        if (quad < 2) {
            #pragma unroll
            for (int r = 0; r < 4; ++r) {
                int no = quad*4 + r;
                if (no < 6) {
                    int jl = jb0 + no;
                    int mtt = jl >> 4, jl16 = jl & 15;
                    phiX[PHX(graph, mtt, tt, jl16)] = acc[r] + bias;
                }
            }
        }
    }
}

// ---------------- output head ----------------
__global__ void zero_out_kernel(float* __restrict__ out) {
    out[threadIdx.x] = 0.f;
}

__global__ void out_kernel(const float* __restrict__ s,
                           const float* __restrict__ w1, const float* __restrict__ b1,
                           const float* __restrict__ w2, const float* __restrict__ b2,
                           float* __restrict__ out) {
    int n = blockIdx.x;
    int f = threadIdx.x;
    __shared__ float sh[NF];
    __shared__ float r2[2];
    sh[f] = s[n*NF + f];
    __syncthreads();
    float acc = b1[f];
    for (int g = 0; g < NF; ++g) acc = fmaf(sh[g], w1[g*NF + f], acc);
    float p = silu_f(acc) * w2[f];
    #pragma unroll
    for (int off = 32; off > 0; off >>= 1) p += __shfl_down(p, off, 64);
    if ((f & 63) == 0) r2[f >> 6] = p;
    __syncthreads();
    if (f == 0) atomicAdd(&out[n / NA], r2[0] + r2[1] + b2[0]);
}

extern "C" void kernel_launch(void* const* d_in, const int* in_sizes, int n_in,
                              void* d_out, int out_size, void* d_ws, size_t ws_size,
                              hipStream_t stream) {
    (void)in_sizes; (void)n_in; (void)out_size; (void)ws_size;
    const float* pos      = (const float*)d_in[1];
    const int*   node_atom= (const int*)  d_in[3];
    const float* emb      = (const float*)d_in[4];
    const float* msg_w1   = (const float*)d_in[5];
    const float* msg_b1   = (const float*)d_in[6];
    const float* msg_w2   = (const float*)d_in[7];
    const float* msg_b2   = (const float*)d_in[8];
    const float* rbf_w    = (const float*)d_in[9];
    const float* rbf_b    = (const float*)d_in[10];
    const float* upd_U    = (const float*)d_in[11];
    const float* upd_V    = (const float*)d_in[12];
    const float* upd_w1   = (const float*)d_in[13];
    const float* upd_b1   = (const float*)d_in[14];
    const float* upd_w2   = (const float*)d_in[15];
    const float* upd_b2   = (const float*)d_in[16];
    const float* out_w1   = (const float*)d_in[17];
    const float* out_b1   = (const float*)d_in[18];
    const float* out_w2   = (const float*)d_in[19];
    const float* out_b2   = (const float*)d_in[20];
    float* out = (float*)d_out;

    float* ws   = (float*)d_ws;
    float* sA   = ws; ws += (size_t)NN*NF;
    float* sB   = ws; ws += (size_t)NN*NF;
    float* vA   = ws; ws += (size_t)NN*F3;
    float* vB   = ws; ws += (size_t)NN*F3;
    float* phiX = ws; ws += (size_t)F3*NN;
    float* vX   = ws; ws += (size_t)F3*NN;
    float* weG  = ws; ws += (size_t)NN*NA;
    float* dirG = ws; ws += (size_t)3*NN*NA;
    short* sp    = (short*)ws;
    short* rbfP  = sp; sp += (size_t)NN*3072;
    short* w1T_h = sp; sp += (size_t)NL*NF*NF;
    short* w1T_l = sp; sp += (size_t)NL*NF*NF;
    short* w2T_h = sp; sp += (size_t)NL*F3*NF;
    short* w2T_l = sp; sp += (size_t)NL*F3*NF;
    short* rbfT_h= sp; sp += (size_t)NL*F3*NK;
    short* rbfT_l= sp; sp += (size_t)NL*F3*NK;
    short* UT_h  = sp; sp += (size_t)NL*NF*NF;
    short* UT_l  = sp; sp += (size_t)NL*NF*NF;
    short* VT_h  = sp; sp += (size_t)NL*NF*NF;
    short* VT_l  = sp; sp += (size_t)NL*NF*NF;
    short* u1T_h = sp; sp += (size_t)NL*NF*2*NF;
    short* u1T_l = sp; sp += (size_t)NL*NF*2*NF;
    short* u2T_h = sp; sp += (size_t)NL*F3*NF;
    short* u2T_l = sp; sp += (size_t)NL*F3*NF;

    prep_kernel<<<dim3(NL*384, 7), 64, 0, stream>>>(msg_w1, msg_w2, rbf_w, upd_U, upd_V, upd_w1, upd_w2,
                                                    w1T_h, w1T_l, w2T_h, w2T_l, rbfT_h, rbfT_l,
                                                    UT_h, UT_l, VT_h, VT_l, u1T_h, u1T_l, u2T_h, u2T_l);
    geom_kernel<<<(NN*NA)/256, 256, 0, stream>>>(pos, weG, dirG, rbfP);
    zero_kernel<<<(F3*NN)/256, 256, 0, stream>>>(vX);
    init_phi_kernel<<<NN/16, 128, 0, stream>>>(emb, node_atom,
                                               w1T_h, w1T_l, msg_b1, w2T_h, w2T_l, msg_b2,
                                               sA, vA, phiX);

    float* sC = sA; float* vC = vA; float* sN = sB; float* vN = vB;
    for (int l = 0; l < NL; ++l) {
        message_kernel<<<NB*8, 512, 0, stream>>>(sC, vC, phiX, vX,
                                                 weG, dirG, rbfP,
                                                 rbfT_h + (size_t)l*F3*NK,
                                                 rbf_b + (size_t)l*F3, sN, vN);
        int lp = (l + 1 < NL) ? (l + 1) : 0;
        update_phi_kernel<<<NN/6, 512, 0, stream>>>(
            UT_h + (size_t)l*NF*NF, VT_h + (size_t)l*NF*NF,
            u1T_h + (size_t)l*NF*2*NF, upd_b1 + (size_t)l*NF,
            u2T_h + (size_t)l*F3*NF, upd_b2 + (size_t)l*F3,
            sN, vN, vX,
            (l + 1 < NL) ? 1 : 0,
            w1T_h + (size_t)lp*NF*NF, msg_b1 + (size_t)lp*NF,
            w2T_h + (size_t)lp*F3*NF, msg_b2 + (size_t)lp*F3,
            phiX);
        float* tp;
        tp = sC; sC = sN; sN = tp;
        tp = vC; vC = vN; vN = tp;
    }
    zero_out_kernel<<<1, NB, 0, stream>>>(out);
    out_kernel<<<NN, NF, 0, stream>>>(sC, out_w1, out_b1, out_w2, out_b2, out);
}

// Round 9
// 535.168 us; speedup vs baseline: 1.4674x; 1.4674x over previous
//
#include <hip/hip_runtime.h>
#include <math.h>

#define NB 96
#define NA 48
#define NF 128
#define NK 64
#define NL 6
#define NN (NB*NA)     // 4608 nodes
#define F3 (3*NF)      // 384
#define CUTF 5.0f
#define GAMMA_F ((float)(1.0 / (0.006103515625 + 1e-9)))
#define PI_F 3.14159265358979323846f

typedef __attribute__((ext_vector_type(8))) short short8;
typedef __attribute__((ext_vector_type(4))) float floatx4;
typedef __attribute__((ext_vector_type(2))) float floatx2;

#define LO2(v) __builtin_shufflevector(v, v, 0, 1)
#define HI2(v) __builtin_shufflevector(v, v, 2, 3)

// phi/vT tile layout: [graph][mt][384 features][16 j]  (wave load = 1KB contiguous)
#define PHX(g, mt, ff, jl) (((((size_t)(g))*3 + (mt))*384 + (ff))*16 + (jl))

__device__ __forceinline__ float silu_f(float x) { return x / (1.0f + expf(-x)); }

__device__ __forceinline__ short f2bf(float x) {
    unsigned u = __builtin_bit_cast(unsigned, x);
    unsigned r = (u + 0x7fffu + ((u >> 16) & 1u)) >> 16;   // RNE
    return (short)r;
}
__device__ __forceinline__ float bf2f(short h) {
    unsigned u = ((unsigned)(unsigned short)h) << 16;
    return __builtin_bit_cast(float, u);
}
__device__ __forceinline__ floatx4 mfma1(short8 a, short8 b, floatx4 c) {
    return __builtin_amdgcn_mfma_f32_16x16x32_bf16(a, b, c, 0, 0, 0);
}
__device__ __forceinline__ floatx4 mfma3(short8 ah, short8 al, short8 bh, short8 bl, floatx4 c) {
    c = __builtin_amdgcn_mfma_f32_16x16x32_bf16(ah, bh, c, 0, 0, 0);
    c = __builtin_amdgcn_mfma_f32_16x16x32_bf16(al, bh, c, 0, 0, 0);
    c = __builtin_amdgcn_mfma_f32_16x16x32_bf16(ah, bl, c, 0, 0, 0);
    return c;
}

// async global->LDS, 16B/lane; lds dest must be wave-uniform base + lane*16
__device__ __forceinline__ void gload_lds16(const void* g, void* l) {
    __builtin_amdgcn_global_load_lds(
        (const __attribute__((address_space(1))) unsigned int*)g,
        (__attribute__((address_space(3))) unsigned int*)l, 16, 0, 0);
}

// ---------------- fused prep: weights -> bf16 hi/lo in MFMA B-FRAGMENT ORDER ----------------
__global__ void prep_kernel(const float* __restrict__ msg_w1, const float* __restrict__ msg_w2,
                            const float* __restrict__ rbf_w, const float* __restrict__ upd_U,
                            const float* __restrict__ upd_V, const float* __restrict__ upd_w1,
                            const float* __restrict__ upd_w2,
                            short* w1T_h, short* w1T_l, short* w2T_h, short* w2T_l,
                            short* rbfT_h, short* rbfT_l, short* UT_h, short* UT_l,
                            short* VT_h, short* VT_l, short* u1T_h, short* u1T_l,
                            short* u2T_h, short* u2T_l) {
    int m = blockIdx.y;
    int l = blockIdx.x / 384;
    int n = blockIdx.x % 384;
    const float* src; short* dh; short* dl; int K, N;
    switch (m) {
      case 0: src = msg_w1; dh = w1T_h; dl = w1T_l; K = NF;   N = NF; break;
      case 1: src = msg_w2; dh = w2T_h; dl = w2T_l; K = NF;   N = F3; break;
      case 2: src = rbf_w;  dh = rbfT_h;dl = rbfT_l;K = NK;   N = F3; break;
      case 3: src = upd_U;  dh = UT_h;  dl = UT_l;  K = NF;   N = NF; break;
      case 4: src = upd_V;  dh = VT_h;  dl = VT_l;  K = NF;   N = NF; break;
      case 5: src = upd_w1; dh = u1T_h; dl = u1T_l; K = 2*NF; N = NF; break;
      default:src = upd_w2; dh = u2T_h; dl = u2T_l; K = NF;   N = F3; break;
    }
    if (n >= N) return;
    for (int k = threadIdx.x; k < K; k += 64) {
        float x = src[((size_t)l*K + k)*N + n];
        short h = f2bf(x);
        size_t off = (size_t)l*N*K
                   + (size_t)((((n>>4)*(K>>5) + (k>>5))*4 + ((k>>3)&3))*128 + (n&15)*8 + (k&7));
        dh[off] = h;
        dl[off] = f2bf(x - bf2f(h));
    }
}

// ---------------- geometry (once): we, dir per (i,j) + rbf*we in tkL FRAGMENT ORDER ----------------
__global__ void __launch_bounds__(256) geom_kernel(const float* __restrict__ pos,
                                                   float* __restrict__ weG,
                                                   float* __restrict__ dirG,
                                                   short* __restrict__ rbfP) {
    int e = blockIdx.x*256 + threadIdx.x;        // e < NN*NA
    int i = e / NA, j = e % NA;
    int b = i / NA, il = i % NA;
    int jg = b*NA + j;
    float dx = pos[i*3+0] - pos[jg*3+0];
    float dy = pos[i*3+1] - pos[jg*3+1];
    float dz = pos[i*3+2] - pos[jg*3+2];
    float d2 = dx*dx + dy*dy + dz*dz;
    float dd = sqrtf((j == il) ? 1.0f : d2);     // matches where(eye,1,d2)
    bool valid = (j != il) && (dd < CUTF);
    float we = valid ? 0.5f*(cosf(PI_F * dd / CUTF) + 1.0f) : 0.0f;
    weG[e] = we;
    float inv = 1.0f / dd;
    dirG[0*(size_t)NN*NA + e] = dx*inv;
    dirG[1*(size_t)NN*NA + e] = dy*inv;
    dirG[2*(size_t)NN*NA + e] = dz*inv;
    int mt = j >> 4, colj = j & 15;
    size_t rb = (size_t)i*3072 + (size_t)(mt*2)*512 + (size_t)colj*8;
    #pragma unroll
    for (int half = 0; half < 2; ++half) {
        #pragma unroll
        for (int c = 0; c < 4; ++c) {
            short8 h8;
            #pragma unroll
            for (int kk = 0; kk < 8; ++kk) {
                int k = half*32 + c*8 + kk;
                float cen = CUTF * (float)k / 63.0f;
                float df = dd - cen;
                h8[kk] = f2bf(__expf(-GAMMA_F * df * df) * we);
            }
            *(short8*)&rbfP[rb + half*512 + c*128] = h8;
        }
    }
}

__global__ void zero_kernel(float* __restrict__ p) {
    p[(size_t)blockIdx.x * blockDim.x + threadIdx.x] = 0.f;
}

// ---------------- init + phi(0) ----------------
__global__ void __launch_bounds__(128) init_phi_kernel(
        const float* __restrict__ emb, const int* __restrict__ node_atom,
        const short* __restrict__ w1T_h, const short* __restrict__ w1T_l,
        const float* __restrict__ b1,
        const short* __restrict__ w2T_h, const short* __restrict__ w2T_l,
        const float* __restrict__ b2,
        float* __restrict__ s, float* __restrict__ v, float* __restrict__ phiX) {
    __shared__ short sH[16*NF], sL[16*NF];
    __shared__ short hH[16*NF], hL[16*NF];
    int t = threadIdx.x;
    int w = t >> 6, lane = t & 63, quad = lane >> 4, col = lane & 15;
    int n0 = blockIdx.x * 16;
    int g = n0 / NA, mt0 = (n0 % NA) >> 4;      // 16-node block lies in one mt
    for (int e = t; e < 16*NF; e += 128) {
        int n = e >> 7, f = e & 127;
        int a = node_atom[n0+n];
        float x = emb[(size_t)a*NF + f];
        s[(size_t)(n0+n)*NF + f] = x;
        short h = f2bf(x);
        int ad = n*NF + (((f >> 3) ^ (n & 7)) << 3) + (f & 7);
        sH[ad] = h; sL[ad] = f2bf(x - bf2f(h));
    }
    for (int e = t; e < 16*F3; e += 128) v[(size_t)n0*F3 + e] = 0.f;
    __syncthreads();
    #pragma unroll
    for (int nt = 0; nt < 4; ++nt) {
        int fh = w*64 + nt*16 + col;
        floatx4 acc = (floatx4){0.f,0.f,0.f,0.f};
        #pragma unroll
        for (int ks = 0; ks < 4; ++ks) {
            int ad = col*NF + (((ks*4 + quad) ^ (col & 7)) << 3);
            size_t off = (size_t)((((w*4 + nt)*4 + ks)*4 + quad)*128) + col*8;
            acc = mfma3(*(short8*)&sH[ad], *(short8*)&sL[ad],
                        *(const short8*)(w1T_h + off), *(const short8*)(w1T_l + off), acc);
        }
        float bias = b1[fh];
        #pragma unroll
        for (int r = 0; r < 4; ++r) {
            int n = quad*4 + r;
            float hv = silu_f(acc[r] + bias);
            short h = f2bf(hv);
            int ad = n*NF + (((fh >> 3) ^ (n & 7)) << 3) + (fh & 7);
            hH[ad] = h; hL[ad] = f2bf(hv - bf2f(h));
        }
    }
    __syncthreads();
    #pragma unroll
    for (int nt = 0; nt < 12; ++nt) {
        int tt = w*192 + nt*16 + col;
        floatx4 acc = (floatx4){0.f,0.f,0.f,0.f};
        #pragma unroll
        for (int ks = 0; ks < 4; ++ks) {
            int ad = col*NF + (((ks*4 + quad) ^ (col & 7)) << 3);
            size_t off = (size_t)((((w*12 + nt)*4 + ks)*4 + quad)*128) + col*8;
            acc = mfma3(*(short8*)&hH[ad], *(short8*)&hL[ad],
                        *(const short8*)(w2T_h + off), *(const short8*)(w2T_l + off), acc);
        }
        float bias = b2[tt];
        floatx4 o;
        #pragma unroll
        for (int r = 0; r < 4; ++r) o[r] = acc[r] + bias;
        *(floatx4*)(phiX + PHX(g, mt0, tt, quad*4)) = o;
    }
}

// ---------------- message: block = (graph, 6-atom tile), 512 thr ----------------
// R9 = R7 verbatim (best verified, 535.5us). R8's register pipeline refuted:
// VGPR hit the 128 cap and spilled (WRITE 9->169MB). Live state sits just
// under 128; no room for a second in-flight vector set.
__global__ void __launch_bounds__(512, 2) message_kernel(
        const float* __restrict__ sIn, const float* __restrict__ vIn,
        const float* __restrict__ phiX, const float* __restrict__ vX,
        const float* __restrict__ weG, const float* __restrict__ dirG,
        const short* __restrict__ rbfP,
        const short* __restrict__ rbfT_h,
        const float* __restrict__ rbf_b_l,
        float* __restrict__ sOut, float* __restrict__ vOut) {
    __shared__ short tkL[36*512];           // 36 KB: 6 atoms x 3 mt x 2 halves x 512
    __shared__ float weL[6][NA];
    __shared__ float dirL[3][6][NA];
    int raw = blockIdx.x;                   // 768 = 8 xcd x 12 graphs x 8 tiles
    int xcd = raw & 7, idx = raw >> 3;
    int graph = xcd + 8*(idx % 12);
    int itile = idx / 12;                   // 0..7
    int i0l = itile*6, jbase = graph*NA;
    int n0 = jbase + i0l;
    int t = threadIdx.x;
    int w = t >> 6, lane = t & 63, quad = lane >> 4, col = lane & 15;
    int f = w*16 + col;
    // async stage rbfP -> tkL: 2304 x 16B, 4 full rounds + 256 tail (waves 0..3)
    {
        const char* gsrc = (const char*)(rbfP + (size_t)n0*3072);
        #pragma unroll
        for (int it = 0; it < 4; ++it)
            gload_lds16(gsrc + (size_t)(t + it*512)*16, (char*)tkL + (size_t)(w*64 + it*512)*16);
        if (w < 4)
            gload_lds16(gsrc + (size_t)(2048 + t)*16, (char*)tkL + (size_t)(2048 + w*64)*16);
    }
    if (t < 288) {
        int ii = t / NA, j = t % NA;
        size_t e = (size_t)(n0 + ii)*NA + j;
        weL[ii][j] = weG[e];
        dirL[0][ii][j] = dirG[0*(size_t)NN*NA + e];
        dirL[1][ii][j] = dirG[1*(size_t)NN*NA + e];
        dirL[2][ii][j] = dirG[2*(size_t)NN*NA + e];
    }
    float rb0 = rbf_b_l[f], rb1 = rbf_b_l[NF+f], rb2 = rbf_b_l[2*NF+f];
    floatx2 rb0v = {rb0, rb0}, rb1v = {rb1, rb1}, rb2v = {rb2, rb2};
    short8 B[3][2];
    #pragma unroll
    for (int g = 0; g < 3; ++g)
        #pragma unroll
        for (int ks = 0; ks < 2; ++ks)
            B[g][ks] = *(const short8*)(rbfT_h + (size_t)((((g*8 + w)*2 + ks)*4 + quad)*128) + col*8);
    __syncthreads();
    float accS[6], av0[6], av1[6], av2[6];
    #pragma unroll
    for (int ia = 0; ia < 6; ++ia) { accS[ia]=0.f; av0[ia]=0.f; av1[ia]=0.f; av2[ia]=0.f; }
    #pragma unroll 1
    for (int mt = 0; mt < 3; ++mt) {
        int jq = quad*4;
        floatx4 p0 = *(const floatx4*)(phiX + PHX(graph, mt, f, jq));
        floatx4 p1 = *(const floatx4*)(phiX + PHX(graph, mt, NF+f, jq));
        floatx4 p2 = *(const floatx4*)(phiX + PHX(graph, mt, 2*NF+f, jq));
        floatx4 u0 = *(const floatx4*)(vX + PHX(graph, mt, 0*NF+f, jq));
        floatx4 u1 = *(const floatx4*)(vX + PHX(graph, mt, 1*NF+f, jq));
        floatx4 u2 = *(const floatx4*)(vX + PHX(graph, mt, 2*NF+f, jq));
        int jl = mt*16 + quad*4;
        #pragma unroll
        for (int ia = 0; ia < 6; ++ia) {
            floatx4 C0 = (floatx4){0.f,0.f,0.f,0.f};
            floatx4 C1 = (floatx4){0.f,0.f,0.f,0.f};
            floatx4 C2 = (floatx4){0.f,0.f,0.f,0.f};
            #pragma unroll
            for (int ks = 0; ks < 2; ++ks) {
                short8 a = *(short8*)&tkL[(((ia*3 + mt)*2 + ks) << 9) + lane*8];
                C0 = mfma1(a, B[0][ks], C0);
                C1 = mfma1(a, B[1][ks], C1);
                C2 = mfma1(a, B[2][ks], C2);
            }
            floatx4 we4 = *(const floatx4*)&weL[ia][jl];
            floatx4 d0 = *(const floatx4*)&dirL[0][ia][jl];
            floatx4 d1 = *(const floatx4*)&dirL[1][ia][jl];
            floatx4 d2 = *(const floatx4*)&dirL[2][ia][jl];
            floatx2 aS = {0.f,0.f}, a0 = {0.f,0.f}, a1 = {0.f,0.f}, a2 = {0.f,0.f};
            // packed pair 0 (r = 0,1)
            {
                floatx2 we2 = LO2(we4);
                floatx2 Wf0 = rb0v*we2 + LO2(C0);
                aS += LO2(p0) * Wf0;
                floatx2 Wf1 = rb1v*we2 + LO2(C1);
                floatx2 x1 = LO2(p1) * Wf1;
                a0 += x1 * LO2(u0);
                a1 += x1 * LO2(u1);
                a2 += x1 * LO2(u2);
                floatx2 Wf2 = rb2v*we2 + LO2(C2);
                floatx2 x2 = LO2(p2) * Wf2;
                a0 += x2 * LO2(d0);
                a1 += x2 * LO2(d1);
                a2 += x2 * LO2(d2);
            }
            // packed pair 1 (r = 2,3)
            {
                floatx2 we2 = HI2(we4);
                floatx2 Wf0 = rb0v*we2 + HI2(C0);
                aS += HI2(p0) * Wf0;
                floatx2 Wf1 = rb1v*we2 + HI2(C1);
                floatx2 x1 = HI2(p1) * Wf1;
                a0 += x1 * HI2(u0);
                a1 += x1 * HI2(u1);
                a2 += x1 * HI2(u2);
                floatx2 Wf2 = rb2v*we2 + HI2(C2);
                floatx2 x2 = HI2(p2) * Wf2;
                a0 += x2 * HI2(d0);
                a1 += x2 * HI2(d1);
                a2 += x2 * HI2(d2);
            }
            accS[ia] += aS.x + aS.y;
            av0[ia]  += a0.x + a0.y;
            av1[ia]  += a1.x + a1.y;
            av2[ia]  += a2.x + a2.y;
        }
    }
    #pragma unroll
    for (int ia = 0; ia < 6; ++ia) {
        int i = n0 + ia;
        float aS = accS[ia], A0 = av0[ia], A1 = av1[ia], A2 = av2[ia];
        aS += __shfl_xor(aS, 16, 64); aS += __shfl_xor(aS, 32, 64);
        A0 += __shfl_xor(A0, 16, 64); A0 += __shfl_xor(A0, 32, 64);
        A1 += __shfl_xor(A1, 16, 64); A1 += __shfl_xor(A1, 32, 64);
        A2 += __shfl_xor(A2, 16, 64); A2 += __shfl_xor(A2, 32, 64);
        if (quad == 0) {
            sOut[(size_t)i*NF + f]        = sIn[(size_t)i*NF + f]        + aS;
            vOut[(size_t)i*F3 + f]        = vIn[(size_t)i*F3 + f]        + A0;
            vOut[(size_t)i*F3 + NF + f]   = vIn[(size_t)i*F3 + NF + f]   + A1;
            vOut[(size_t)i*F3 + 2*NF + f] = vIn[(size_t)i*F3 + 2*NF + f] + A2;
        }
    }
}

// ---------------- update (+ fused phi): 6 nodes/block, 512 thr, hi-only GEMMs ----------------
__global__ void __launch_bounds__(512) update_phi_kernel(
        const short* __restrict__ UT_h, const short* __restrict__ VT_h,
        const short* __restrict__ u1T_h, const float* __restrict__ b1,
        const short* __restrict__ u2T_h, const float* __restrict__ b2,
        float* __restrict__ s, float* __restrict__ v, float* __restrict__ vX,
        int doPhi,
        const short* __restrict__ pw1_h, const float* __restrict__ pb1,
        const short* __restrict__ pw2_h, const float* __restrict__ pb2,
        float* __restrict__ phiX) {
    __shared__ short A1h[48*NF], A1l[48*NF];   // v (hi for MFMA, hi+lo for epilogue reconstruct)
    __shared__ short A2h[16*256];              // [s ; Vn] hi; reused for s_new (phi A)
    __shared__ short hH[16*NF];
    __shared__ float sF[6*132];
    int t = threadIdx.x;
    int w = t >> 6, lane = t & 63, quad = lane >> 4, col = lane & 15;
    int raw = blockIdx.x;                   // 768 = 8 xcd x 12 graphs x 8 tiles
    int xcd = raw & 7, idx = raw >> 3;
    int graph = xcd + 8*(idx % 12);
    int jb0 = (idx / 12)*6;                 // local node base within graph
    int n0 = graph*NA + jb0;
    int f = w*16 + col;
    for (int e = t; e < 6*F3; e += 512) {
        int n = e / F3, cf = e % F3;
        int c = cf >> 7, ff = cf & 127;
        float x = v[(size_t)(n0+n)*F3 + cf];
        int row = c*16 + n;
        short h = f2bf(x);
        int ad = row*NF + (((ff >> 3) ^ (row & 7)) << 3) + (ff & 7);
        A1h[ad] = h; A1l[ad] = f2bf(x - bf2f(h));
    }
    for (int e = t; e < 6*NF; e += 512) {
        int n = e >> 7, ff = e & 127;
        float x = s[(size_t)(n0+n)*NF + ff];
        sF[n*132 + ff] = x;
        int ad = n*256 + (((ff >> 3) ^ (n & 7)) << 3) + (ff & 7);
        A2h[ad] = f2bf(x);
    }
    __syncthreads();
    floatx4 Uacc[3], Vacc[3];
    #pragma unroll
    for (int mt = 0; mt < 3; ++mt) { Uacc[mt] = (floatx4){0.f,0.f,0.f,0.f}; Vacc[mt] = (floatx4){0.f,0.f,0.f,0.f}; }
    #pragma unroll
    for (int ks = 0; ks < 4; ++ks) {
        size_t off = (size_t)(((w*4 + ks)*4 + quad)*128) + col*8;
        short8 BU = *(const short8*)(UT_h + off);
        short8 BV = *(const short8*)(VT_h + off);
        #pragma unroll
        for (int mt = 0; mt < 3; ++mt) {
            int row = mt*16 + col;
            int ad = row*NF + (((ks*4 + quad) ^ (row & 7)) << 3);
            short8 ah = *(short8*)&A1h[ad];
            Uacc[mt] = mfma1(ah, BU, Uacc[mt]);
            Vacc[mt] = mfma1(ah, BV, Vacc[mt]);
        }
    }
    if (quad < 2) {
        #pragma unroll
        for (int r = 0; r < 4; ++r) {
            int n = quad*4 + r;          // n < 8
            if (n < 6) {
                float v0 = Vacc[0][r], v1 = Vacc[1][r], v2 = Vacc[2][r];
                float vn = sqrtf(v0*v0 + v1*v1 + v2*v2 + 1e-8f);
                int ad = n*256 + ((((128 + f) >> 3) ^ (n & 7)) << 3) + (f & 7);
                A2h[ad] = f2bf(vn);
            }
        }
    }
    __syncthreads();
    {
        floatx4 H = (floatx4){0.f,0.f,0.f,0.f};
        #pragma unroll
        for (int ks = 0; ks < 8; ++ks) {
            int ad = col*256 + (((ks*4 + quad) ^ (col & 7)) << 3);
            short8 ah = *(short8*)&A2h[ad];
            size_t off = (size_t)(((w*8 + ks)*4 + quad)*128) + col*8;
            H = mfma1(ah, *(const short8*)(u1T_h + off), H);
        }
        float bias = b1[f];
        if (quad < 2) {
            #pragma unroll
            for (int r = 0; r < 4; ++r) {
                int n = quad*4 + r;
                if (n < 6) {
                    float hv = silu_f(H[r] + bias);
                    int ad = n*NF + (((f >> 3) ^ (n & 7)) << 3) + (f & 7);
                    hH[ad] = f2bf(hv);
                }
            }
        }
    }
    __syncthreads();
    floatx4 O[3];
    #pragma unroll
    for (int gg = 0; gg < 3; ++gg) O[gg] = (floatx4){0.f,0.f,0.f,0.f};
    #pragma unroll
    for (int ks = 0; ks < 4; ++ks) {
        int ad = col*NF + (((ks*4 + quad) ^ (col & 7)) << 3);
        short8 ah = *(short8*)&hH[ad];
        #pragma unroll
        for (int gg = 0; gg < 3; ++gg) {
            size_t off = (size_t)((((gg*8 + w)*4 + ks)*4 + quad)*128) + col*8;
            O[gg] = mfma1(ah, *(const short8*)(u2T_h + off), O[gg]);
        }
    }
    __syncthreads();        // A2h free -> reuse for s_new (phi A operand)
    short* pH = A2h;
    if (quad < 2) {
        float bavv = b2[f], basv = b2[NF + f], bass = b2[2*NF + f];
        #pragma unroll
        for (int r = 0; r < 4; ++r) {
            int n = quad*4 + r;          // n < 8
            if (n < 6) {
                float avv = O[0][r] + bavv;
                float asv = O[1][r] + basv;
                float ass = O[2][r] + bass;
                float dot = Uacc[0][r]*Vacc[0][r] + Uacc[1][r]*Vacc[1][r] + Uacc[2][r]*Vacc[2][r];
                float snew = sF[n*132 + f] + asv*dot + ass;
                s[(size_t)(n0+n)*NF + f] = snew;
                int adS = n*NF + (((f >> 3) ^ (n & 7)) << 3) + (f & 7);
                pH[adS] = f2bf(snew);
                int jl = jb0 + n;
                int mtt = jl >> 4, jl16 = jl & 15;
                #pragma unroll
                for (int c = 0; c < 3; ++c) {
                    int row = c*16 + n;
                    int ad = row*NF + (((f >> 3) ^ (row & 7)) << 3) + (f & 7);
                    float vold = bf2f(A1h[ad]) + bf2f(A1l[ad]);   // exact fp32 v_old
                    float vnew = vold + avv*Uacc[c][r];
                    v[(size_t)(n0+n)*F3 + c*NF + f] = vnew;
                    vX[PHX(graph, mtt, c*NF + f, jl16)] = vnew;
                }
            }
        }
    }
    if (!doPhi) return;
    __syncthreads();
    // phi GEMM1: wave w -> feature tile w (fh = w*16+col)
    {
        floatx4 acc = (floatx4){0.f,0.f,0.f,0.f};
        #pragma unroll
        for (int ks = 0; ks < 4; ++ks) {
            int ad = col*NF + (((ks*4 + quad) ^ (col & 7)) << 3);
            size_t off = (size_t)(((w*4 + ks)*4 + quad)*128) + col*8;
            acc = mfma1(*(short8*)&pH[ad], *(const short8*)(pw1_h + off), acc);
        }
        float bias = pb1[f];
        if (quad < 2) {
            #pragma unroll
            for (int r = 0; r < 4; ++r) {
                int n = quad*4 + r;
                if (n < 6) {
                    float hv = silu_f(acc[r] + bias);
                    int ad = n*NF + (((f >> 3) ^ (n & 7)) << 3) + (f & 7);
                    hH[ad] = f2bf(hv);
                }
            }
        }
    }
    __syncthreads();
    // phi GEMM2: 8 waves x 3 tiles (tt = (w*3+nt)*16 + col)
    #pragma unroll
    for (int nt = 0; nt < 3; ++nt) {
        int tt = (w*3 + nt)*16 + col;
        floatx4 acc = (floatx4){0.f,0.f,0.f,0.f};
        #pragma unroll
        for (int ks = 0; ks < 4; ++ks) {
            int ad = col*NF + (((ks*4 + quad) ^ (col & 7)) << 3);
            size_t off = (size_t)((((w*3 + nt)*4 + ks)*4 + quad)*128) + col*8;
            acc = mfma1(*(short8*)&hH[ad], *(const short8*)(pw2_h + off), acc);
        }
        float bias = pb2[tt];
        if (quad < 2) {
            #pragma unroll
            for (int r = 0; r < 4; ++r) {
                int no = quad*4 + r;
                if (no < 6) {
                    int jl = jb0 + no;
                    int mtt = jl >> 4, jl16 = jl & 15;
                    phiX[PHX(graph, mtt, tt, jl16)] = acc[r] + bias;
                }
            }
        }
    }
}

// ---------------- output head ----------------
__global__ void zero_out_kernel(float* __restrict__ out) {
    out[threadIdx.x] = 0.f;
}

__global__ void out_kernel(const float* __restrict__ s,
                           const float* __restrict__ w1, const float* __restrict__ b1,
                           const float* __restrict__ w2, const float* __restrict__ b2,
                           float* __restrict__ out) {
    int n = blockIdx.x;
    int f = threadIdx.x;
    __shared__ float sh[NF];
    __shared__ float r2[2];
    sh[f] = s[n*NF + f];
    __syncthreads();
    float acc = b1[f];
    for (int g = 0; g < NF; ++g) acc = fmaf(sh[g], w1[g*NF + f], acc);
    float p = silu_f(acc) * w2[f];
    #pragma unroll
    for (int off = 32; off > 0; off >>= 1) p += __shfl_down(p, off, 64);
    if ((f & 63) == 0) r2[f >> 6] = p;
    __syncthreads();
    if (f == 0) atomicAdd(&out[n / NA], r2[0] + r2[1] + b2[0]);
}

extern "C" void kernel_launch(void* const* d_in, const int* in_sizes, int n_in,
                              void* d_out, int out_size, void* d_ws, size_t ws_size,
                              hipStream_t stream) {
    (void)in_sizes; (void)n_in; (void)out_size; (void)ws_size;
    const float* pos      = (const float*)d_in[1];
    const int*   node_atom= (const int*)  d_in[3];
    const float* emb      = (const float*)d_in[4];
    const float* msg_w1   = (const float*)d_in[5];
    const float* msg_b1   = (const float*)d_in[6];
    const float* msg_w2   = (const float*)d_in[7];
    const float* msg_b2   = (const float*)d_in[8];
    const float* rbf_w    = (const float*)d_in[9];
    const float* rbf_b    = (const float*)d_in[10];
    const float* upd_U    = (const float*)d_in[11];
    const float* upd_V    = (const float*)d_in[12];
    const float* upd_w1   = (const float*)d_in[13];
    const float* upd_b1   = (const float*)d_in[14];
    const float* upd_w2   = (const float*)d_in[15];
    const float* upd_b2   = (const float*)d_in[16];
    const float* out_w1   = (const float*)d_in[17];
    const float* out_b1   = (const float*)d_in[18];
    const float* out_w2   = (const float*)d_in[19];
    const float* out_b2   = (const float*)d_in[20];
    float* out = (float*)d_out;

    float* ws   = (float*)d_ws;
    float* sA   = ws; ws += (size_t)NN*NF;
    float* sB   = ws; ws += (size_t)NN*NF;
    float* vA   = ws; ws += (size_t)NN*F3;
    float* vB   = ws; ws += (size_t)NN*F3;
    float* phiX = ws; ws += (size_t)F3*NN;
    float* vX   = ws; ws += (size_t)F3*NN;
    float* weG  = ws; ws += (size_t)NN*NA;
    float* dirG = ws; ws += (size_t)3*NN*NA;
    short* sp    = (short*)ws;
    short* rbfP  = sp; sp += (size_t)NN*3072;
    short* w1T_h = sp; sp += (size_t)NL*NF*NF;
    short* w1T_l = sp; sp += (size_t)NL*NF*NF;
    short* w2T_h = sp; sp += (size_t)NL*F3*NF;
    short* w2T_l = sp; sp += (size_t)NL*F3*NF;
    short* rbfT_h= sp; sp += (size_t)NL*F3*NK;
    short* rbfT_l= sp; sp += (size_t)NL*F3*NK;
    short* UT_h  = sp; sp += (size_t)NL*NF*NF;
    short* UT_l  = sp; sp += (size_t)NL*NF*NF;
    short* VT_h  = sp; sp += (size_t)NL*NF*NF;
    short* VT_l  = sp; sp += (size_t)NL*NF*NF;
    short* u1T_h = sp; sp += (size_t)NL*NF*2*NF;
    short* u1T_l = sp; sp += (size_t)NL*NF*2*NF;
    short* u2T_h = sp; sp += (size_t)NL*F3*NF;
    short* u2T_l = sp; sp += (size_t)NL*F3*NF;

    prep_kernel<<<dim3(NL*384, 7), 64, 0, stream>>>(msg_w1, msg_w2, rbf_w, upd_U, upd_V, upd_w1, upd_w2,
                                                    w1T_h, w1T_l, w2T_h, w2T_l, rbfT_h, rbfT_l,
                                                    UT_h, UT_l, VT_h, VT_l, u1T_h, u1T_l, u2T_h, u2T_l);
    geom_kernel<<<(NN*NA)/256, 256, 0, stream>>>(pos, weG, dirG, rbfP);
    zero_kernel<<<(F3*NN)/256, 256, 0, stream>>>(vX);
    init_phi_kernel<<<NN/16, 128, 0, stream>>>(emb, node_atom,
                                               w1T_h, w1T_l, msg_b1, w2T_h, w2T_l, msg_b2,
                                               sA, vA, phiX);

    float* sC = sA; float* vC = vA; float* sN = sB; float* vN = vB;
    for (int l = 0; l < NL; ++l) {
        message_kernel<<<NB*8, 512, 0, stream>>>(sC, vC, phiX, vX,
                                                 weG, dirG, rbfP,
                                                 rbfT_h + (size_t)l*F3*NK,
                                                 rbf_b + (size_t)l*F3, sN, vN);
        int lp = (l + 1 < NL) ? (l + 1) : 0;
        update_phi_kernel<<<NN/6, 512, 0, stream>>>(
            UT_h + (size_t)l*NF*NF, VT_h + (size_t)l*NF*NF,
            u1T_h + (size_t)l*NF*2*NF, upd_b1 + (size_t)l*NF,
            u2T_h + (size_t)l*F3*NF, upd_b2 + (size_t)l*F3,
            sN, vN, vX,
            (l + 1 < NL) ? 1 : 0,
            w1T_h + (size_t)lp*NF*NF, msg_b1 + (size_t)lp*NF,
            w2T_h + (size_t)lp*F3*NF, msg_b2 + (size_t)lp*F3,
            phiX);
        float* tp;
        tp = sC; sC = sN; sN = tp;
        tp = vC; vC = vN; vN = tp;
    }
    zero_out_kernel<<<1, NB, 0, stream>>>(out);
    out_kernel<<<NN, NF, 0, stream>>>(sC, out_w1, out_b1, out_w2, out_b2, out);
}